// Round 7
// baseline (311.412 us; speedup 1.0000x reference)
//
#include <hip/hip_runtime.h>
#include <hip/hip_bf16.h>
#include <cmath>

#define NN 500000
#define CC 256
#define HH 8
#define DD 32
#define GG 4096

typedef short bf16x8 __attribute__((ext_vector_type(8)));   // 8 bf16 bit patterns (4 VGPRs)
typedef float f32x4 __attribute__((ext_vector_type(4)));

// ---------- workspace layout ----------
#define OFF_START 0
#define OFF_FLAG  16400

__device__ __forceinline__ int get_batch(const void* b, int i, int is64) {
    return is64 ? (int)((const long long*)b)[i] : ((const int*)b)[i];
}

__global__ void detect_kernel(const int* __restrict__ b32, int n, int* __restrict__ flag) {
    if (threadIdx.x == 0 && blockIdx.x == 0) {
        int a = b32[(n / 2) | 1];
        int b = b32[(n - 2) | 1];
        int c = b32[((n / 2) + (n / 4)) | 1];
        *flag = (a == 0 && b == 0 && c == 0) ? 1 : 0;
    }
}

__global__ void seg_offsets_kernel(const void* __restrict__ batch, const int* __restrict__ flag,
                                   int n, int g_total, int* __restrict__ start) {
    int is64 = *flag;
    int i = blockIdx.x * blockDim.x + threadIdx.x;
    if (i >= n) return;
    int b = get_batch(batch, i, is64);
    int prev = (i == 0) ? -1 : get_batch(batch, i - 1, is64);
    for (int g = prev + 1; g <= b; ++g) start[g] = i;
    if (i == n - 1) {
        for (int g = b + 1; g <= g_total; ++g) start[g] = n;
    }
}

__device__ __forceinline__ unsigned pack_bf2(float a, float b) {
    __hip_bfloat162 h2 = __float22bfloat162_rn(make_float2(a, b));
    unsigned u;
    __builtin_memcpy(&u, &h2, 4);
    return u;
}
__device__ __forceinline__ float ubf_lo(unsigned u) { return __uint_as_float(u << 16); }
__device__ __forceinline__ float ubf_hi(unsigned u) { return __uint_as_float(u & 0xffff0000u); }

// One block per graph; each WAVE independently owns 8-node tiles (stride 32) in a
// 2-deep pipeline: while tile t is packed/gated/accumulated, tile t+1's global
// loads are in flight (32 prefetch VGPRs). Gate via MFMA (Wg B-frags in regs),
// exp-direct (gate ~ N(0,1): fp32-safe), weighted accumulation from bf16 LDS.
__global__ __launch_bounds__(256, 4) void fused_kernel(const float* __restrict__ x,
                                                       const int* __restrict__ start,
                                                       const float* __restrict__ Wg,
                                                       const float* __restrict__ Wn,
                                                       const float* __restrict__ bn,
                                                       float* __restrict__ out) {
    __shared__ float4 xb4[2048];        // 32 KB: wave w owns [w*512, (w+1)*512); stage uses first 4 KB of slice
    __shared__ uint4 e_q[32];           // 512 B: e[node][8 heads] bf16, wave w owns [w*8, w*8+8)
    __shared__ float red[32];           // per-wave per-head s partials
    __shared__ float inv_s[HH];

    int g = blockIdx.x, t = threadIdx.x;
    int s0 = start[g], s1 = start[g + 1], len = s1 - s0;

    if (len == 0) { out[(size_t)g * (HH * DD) + t] = 0.f; return; }

    const int w  = t >> 6;      // wave id
    const int l  = t & 63;      // lane
    const int lr = l & 15;      // MFMA row/col index (head for B/D)
    const int lk = l >> 4;      // MFMA k-group
    const int sn = l >> 3;      // stage: node-in-tile (0..7)
    const int sub = l & 7;      // stage: 1/8-row slice

    const float4* x4 = reinterpret_cast<const float4*>(x);
    char* slice = (char*)xb4 + w * 8192;            // this wave's 8 KB region

    // ---- issue prefetch for tile 0 FIRST (latency covered by Wg build below)
    float4 pf[8];
    {
        int n = w * 8 + sn;
        if (n < len) {
            const float4* xr = x4 + (size_t)(s0 + n) * (CC / 4) + sub;
#pragma unroll
            for (int j = 0; j < 8; ++j) pf[j] = xr[j * 8];
        }
    }

    // ---- Wg B-fragments, constant in registers: wb[tt][j] = Wg[head=lr][tt*32+lk*8+j]
    bf16x8 wb[8];
    {
        int hc = lr & 7;
        const float4* wp4 = reinterpret_cast<const float4*>(Wg + hc * CC + lk * 8);
#pragma unroll
        for (int tt = 0; tt < 8; ++tt) {
            float4 wa = wp4[tt * 8], wbv = wp4[tt * 8 + 1];
            unsigned u01 = pack_bf2(wa.x, wa.y), u23 = pack_bf2(wa.z, wa.w);
            unsigned u45 = pack_bf2(wbv.x, wbv.y), u67 = pack_bf2(wbv.z, wbv.w);
            if (lr < 8) {
                wb[tt][0] = (short)(u01 & 0xffff); wb[tt][1] = (short)(u01 >> 16);
                wb[tt][2] = (short)(u23 & 0xffff); wb[tt][3] = (short)(u23 >> 16);
                wb[tt][4] = (short)(u45 & 0xffff); wb[tt][5] = (short)(u45 >> 16);
                wb[tt][6] = (short)(u67 & 0xffff); wb[tt][7] = (short)(u67 >> 16);
            } else {
#pragma unroll
                for (int j = 0; j < 8; ++j) wb[tt][j] = 0;
            }
        }
    }

    float acc[HH][4];
#pragma unroll
    for (int h = 0; h < HH; ++h)
#pragma unroll
        for (int e = 0; e < 4; ++e) acc[h][e] = 0.f;
    float s_part = 0.f;

    // ================= main loop: 8-node tiles, 2-deep pipeline =================
    for (int tb = w * 8; tb < len; tb += 32) {
        int tl = (len - tb < 8) ? (len - tb) : 8;

        // ---- stage: pack prefetched fp32 -> bf16 LDS (swizzled)
        if (sn < tl) {
            char* rb = slice + sn * 512;
            unsigned swz = (unsigned)(sn << 4);
#pragma unroll
            for (int j = 0; j < 8; ++j) {
                uint2 p;
                p.x = pack_bf2(pf[j].x, pf[j].y);
                p.y = pack_bf2(pf[j].z, pf[j].w);
                *reinterpret_cast<uint2*>(rb + (((unsigned)((j * 8 + sub) * 8)) ^ swz)) = p;
            }
        }

        // ---- issue prefetch for NEXT tile (in flight during MFMA+exp+pass2)
        {
            int n = tb + 32 + sn;
            if (n < len) {
                const float4* xr = x4 + (size_t)(s0 + n) * (CC / 4) + sub;
#pragma unroll
                for (int j = 0; j < 8; ++j) pf[j] = xr[j * 8];
            }
        }

        // ---- gate via MFMA: D[node, head] = sum_c X[node,c] * Wg[head,c]
        // A-rows duplicated (lr&7): rows >= tl are garbage but MFMA rows are independent.
        f32x4 d = {0.f, 0.f, 0.f, 0.f};
        {
            int ar = lr & 7;
            char* rb = slice + ar * 512;
            unsigned swz = (unsigned)(ar << 4);
#pragma unroll
            for (int tt = 0; tt < 8; ++tt) {
                bf16x8 a = *reinterpret_cast<bf16x8*>(rb + (((unsigned)(lk * 16 + tt * 64)) ^ swz));
                d = __builtin_amdgcn_mfma_f32_16x16x32_bf16(a, wb[tt], d, 0, 0, 0);
            }
        }

        // ---- e = exp(gate) (predicated), s partial, bf16 e -> LDS [node][head]
        {
            unsigned short* ep = reinterpret_cast<unsigned short*>(e_q) + w * 64;
#pragma unroll
            for (int r = 0; r < 4; ++r) {
                int n = lk * 4 + r;
                float e = 0.f;
                if (n < tl && lr < 8) { e = __expf(d[r]); s_part += e; }
                if (n < 8 && lr < 8) ep[n * 8 + lr] = (unsigned short)(pack_bf2(e, 0.f) & 0xffff);
            }
        }

        // ---- pass2: acc[h][c'] += e[i,h] * x[i, l*4+c']   (all from own LDS slice)
        {
            const uint4* eq = e_q + w * 8;
            for (int i = 0; i < tl; ++i) {
                uint4 eu = eq[i];
                unsigned swz = (unsigned)((i & 7) << 4);
                uint2 xu = *reinterpret_cast<uint2*>(slice + i * 512 + (((unsigned)(l * 8)) ^ swz));
                float x0 = ubf_lo(xu.x), x1 = ubf_hi(xu.x);
                float x2 = ubf_lo(xu.y), x3 = ubf_hi(xu.y);
                float e0 = ubf_lo(eu.x), e1 = ubf_hi(eu.x);
                float e2 = ubf_lo(eu.y), e3 = ubf_hi(eu.y);
                float e4 = ubf_lo(eu.z), e5 = ubf_hi(eu.z);
                float e6 = ubf_lo(eu.w), e7 = ubf_hi(eu.w);
                acc[0][0] += e0 * x0; acc[0][1] += e0 * x1; acc[0][2] += e0 * x2; acc[0][3] += e0 * x3;
                acc[1][0] += e1 * x0; acc[1][1] += e1 * x1; acc[1][2] += e1 * x2; acc[1][3] += e1 * x3;
                acc[2][0] += e2 * x0; acc[2][1] += e2 * x1; acc[2][2] += e2 * x2; acc[2][3] += e2 * x3;
                acc[3][0] += e3 * x0; acc[3][1] += e3 * x1; acc[3][2] += e3 * x2; acc[3][3] += e3 * x3;
                acc[4][0] += e4 * x0; acc[4][1] += e4 * x1; acc[4][2] += e4 * x2; acc[4][3] += e4 * x3;
                acc[5][0] += e5 * x0; acc[5][1] += e5 * x1; acc[5][2] += e5 * x2; acc[5][3] += e5 * x3;
                acc[6][0] += e6 * x0; acc[6][1] += e6 * x1; acc[6][2] += e6 * x2; acc[6][3] += e6 * x3;
                acc[7][0] += e7 * x0; acc[7][1] += e7 * x1; acc[7][2] += e7 * x2; acc[7][3] += e7 * x3;
            }
        }
    }

    // ================= epilogue =================
    // s: sum the 4 k-groups in-wave, stash per-wave per-head partials
    s_part += __shfl_xor(s_part, 16);
    s_part += __shfl_xor(s_part, 32);
    if (l < 8) red[w * 8 + l] = s_part;

    // dump this wave's xw partials into ITS OWN slice: [w][h][cg] float4
#pragma unroll
    for (int h = 0; h < HH; ++h)
        xb4[w * 512 + h * 64 + l] = make_float4(acc[h][0], acc[h][1], acc[h][2], acc[h][3]);
    __syncthreads();

    if (t < HH) inv_s[t] = 1.f / (red[t] + red[8 + t] + red[16 + t] + red[24 + t]);

    // reduce the 4 wave-partials in place (into wave-0 region)
    float* xwf = reinterpret_cast<float*>(xb4);
    for (int idx = t; idx < HH * CC; idx += 256)
        xwf[idx] = xwf[idx] + xwf[2048 + idx] + xwf[4096 + idx] + xwf[6144 + idx];
    __syncthreads();

    // projection: out[g, h*32+d] = bn + inv_s[h] * sum_c xw[h,c]*Wn[h,c,d]
    int ph = t >> 5, pd = t & 31;
    const float* wnp = Wn + (size_t)ph * CC * DD + pd;
    float o = 0.f;
#pragma unroll 8
    for (int c0 = 0; c0 < CC; ++c0) {
        int ce = (c0 + 4 * ph) & 255;      // rotate start per head -> distinct banks
        o += xwf[ph * 256 + ce] * wnp[(size_t)ce * DD];
    }
    o = bn[ph * DD + pd] + inv_s[ph] * o;
    out[(size_t)g * (HH * DD) + t] = o;
}

extern "C" void kernel_launch(void* const* d_in, const int* in_sizes, int n_in,
                              void* d_out, int out_size, void* d_ws, size_t ws_size,
                              hipStream_t stream) {
    const float* x     = (const float*)d_in[0];
    const void*  batch = d_in[1];
    const float* Wg    = (const float*)d_in[2];
    const float* Wn    = (const float*)d_in[3];
    const float* bn    = (const float*)d_in[4];
    float* out = (float*)d_out;

    char* w = (char*)d_ws;
    int* startp = (int*)(w + OFF_START);
    int* flag   = (int*)(w + OFF_FLAG);

    detect_kernel<<<1, 64, 0, stream>>>((const int*)batch, NN, flag);
    seg_offsets_kernel<<<(NN + 255) / 256, 256, 0, stream>>>(batch, flag, NN, GG, startp);
    fused_kernel<<<GG, 256, 0, stream>>>(x, startp, Wg, Wn, bn, out);
}